// Round 18
// baseline (220.436 us; speedup 1.0000x reference)
//
#include <hip/hip_runtime.h>
#include <hip/hip_cooperative_groups.h>

namespace cg = cooperative_groups;

// One-way Chamfer (L1, K=1): out[0] = mean_i min_j ||x_i - y_j||_1 ; out[1..N] = 0
// N = M = 16384, D = 3, fp32.
//
// R18: R17's 7-dispatch pipeline spent ~60us on launch ramps + low-occupancy
// latency. Fuse EVERYTHING into one cooperative kernel (harness supports
// hipLaunchCooperativeKernel): P0 zero, P1 hist, P2 scans, P3 scatter,
// P4 bound+window per group (s_load dbuf SGPR broadcast), P5 sum.
// Exactness: group window [qxmin-mm, qxmax+mm] (proper wave min/max now,
// +-1 slab slack for FP trunc) contains every member's L1 ball; extra real
// points can never dip below the global min; overrun (<=15 pts) lands on
// real points or the +inf pad. qmin == d_true exactly -> deterministic.

#define NB   1024
#define LOX  (-64.0f)
#define INVW 8.0f
#define NPAD 16
#define GRID 256
#define TPB  256

typedef float sf16 __attribute__((ext_vector_type(16)));
typedef float sf8  __attribute__((ext_vector_type(8)));

__device__ __forceinline__ int rfl(int v) {
    return __builtin_amdgcn_readfirstlane(v);
}
__device__ __forceinline__ const float* upf(const float* p) {
    union { const float* p; unsigned u[2]; } a;
    a.p = p;
    a.u[0] = (unsigned)__builtin_amdgcn_readfirstlane((int)a.u[0]);
    a.u[1] = (unsigned)__builtin_amdgcn_readfirstlane((int)a.u[1]);
    return a.p;
}

#define SLOAD24(B16, B8, PTR, O16, O8)                                     \
  asm volatile("s_load_dwordx16 %0, %2, " O16 "\n\t"                       \
               "s_load_dwordx8  %1, %2, " O8                               \
               : "=s"(B16), "=s"(B8) : "s"(PTR));

#define SWAIT(B16, B8)                                                     \
  asm volatile("s_waitcnt lgkmcnt(0)" : "+s"(B16), "+s"(B8));

#define DIST2S(MR, AXv, AYv, AZv, Y0X, Y0Y, Y0Z, Y1X, Y1Y, Y1Z)           \
  {                                                                        \
    float t0, t1, t2, t3, t4;                                              \
    asm("v_sub_f32 %1, %9, %6\n\t"                                         \
        "v_sub_f32 %2, %10, %7\n\t"                                        \
        "v_sub_f32 %3, %11, %8\n\t"                                        \
        "v_sub_f32 %4, %12, %6\n\t"                                        \
        "v_sub_f32 %5, %13, %7\n\t"                                        \
        "v_add_f32 %1, |%1|, |%2|\n\t"                                     \
        "v_sub_f32 %2, %14, %8\n\t"                                        \
        "v_add_f32 %4, |%4|, |%5|\n\t"                                     \
        "v_add_f32 %1, %1, |%3|\n\t"                                       \
        "v_add_f32 %4, %4, |%2|\n\t"                                       \
        "v_min3_f32 %0, %0, %1, %4"                                        \
        : "+v"(MR), "=&v"(t0), "=&v"(t1), "=&v"(t2), "=&v"(t3), "=&v"(t4)  \
        : "v"(AXv), "v"(AYv), "v"(AZv),                                    \
          "s"(Y0X), "s"(Y0Y), "s"(Y0Z), "s"(Y1X), "s"(Y1Y), "s"(Y1Z));    \
  }

#define COMPUTE8_1(G16, G8)                                                \
  {                                                                        \
    DIST2S(m, qx, qy, qz, G16[0], G16[1], G16[2], G16[3], G16[4], G16[5]); \
    DIST2S(m, qx, qy, qz, G16[6], G16[7], G16[8], G16[9], G16[10], G16[11]);\
    DIST2S(m, qx, qy, qz, G16[12], G16[13], G16[14], G16[15], G8[0], G8[1]);\
    DIST2S(m, qx, qy, qz, G8[2], G8[3], G8[4], G8[5], G8[6], G8[7]);       \
  }

__device__ __forceinline__ int slab_of(float x) {
    int b = (int)((x - LOX) * INVW);
    return (b < 0) ? 0 : ((b > NB - 1) ? NB - 1 : b);
}

__global__ __launch_bounds__(TPB) void fused_kernel(
    const float* __restrict__ pc1, const float* __restrict__ flow,
    const float* __restrict__ pc2, int* __restrict__ hist2,
    int* __restrict__ histq, int* __restrict__ base2,
    int* __restrict__ cursor2, int* __restrict__ cursorq,
    float* __restrict__ pts2, float4* __restrict__ qs,
    float* __restrict__ qmin, float* __restrict__ out,
    int N, int M, int out_size, float invN) {
    cg::grid_group grid = cg::this_grid();

    __shared__ int   ibuf[TPB];
    __shared__ float smem[4][64];
    __shared__ float sm4[64];
    __shared__ float smm;

    const int t = threadIdx.x, b = blockIdx.x;
    const int gtid = b * TPB + t;
    const int gstride = GRID * TPB;

    // ---- P0: zero hists, output zeros, +inf pad ----
    for (int k = gtid; k < 2 * NB; k += gstride) hist2[k] = 0;  // hist2+histq contiguous
    for (int k = gtid; k + 1 < out_size; k += gstride) out[1 + k] = 0.0f;
    if (gtid < 3 * NPAD) pts2[3 * M + gtid] = 1.0e30f;
    grid.sync();

    // ---- P1: histograms ----
    for (int j = gtid; j < M; j += gstride)
        atomicAdd(&hist2[slab_of(pc2[3 * j])], 1);
    for (int j = gtid; j < N; j += gstride)
        atomicAdd(&histq[slab_of(pc1[3 * j] + flow[3 * j])], 1);
    grid.sync();

    // ---- P2: exclusive scans (block 0: hist2 -> base2/cursor2; block 1: histq -> cursorq) ----
    if (b < 2) {
        const int* h = (b == 0) ? hist2 : histq;
        const int s0 = h[4 * t], s1 = h[4 * t + 1], s2 = h[4 * t + 2], s3 = h[4 * t + 3];
        const int lsum = s0 + s1 + s2 + s3;
        ibuf[t] = lsum;
        __syncthreads();
        for (int off = 1; off < TPB; off <<= 1) {
            int v = (t >= off) ? ibuf[t - off] : 0;
            __syncthreads();
            ibuf[t] += v;
            __syncthreads();
        }
        const int ex = ibuf[t] - lsum;
        if (b == 0) {
            base2[4 * t] = ex;                cursor2[4 * t] = ex;
            base2[4 * t + 1] = ex + s0;       cursor2[4 * t + 1] = ex + s0;
            base2[4 * t + 2] = ex + s0 + s1;  cursor2[4 * t + 2] = ex + s0 + s1;
            base2[4 * t + 3] = ex + s0 + s1 + s2;
            cursor2[4 * t + 3] = ex + s0 + s1 + s2;
            if (t == TPB - 1) base2[NB] = ex + lsum;
        } else {
            cursorq[4 * t] = ex;
            cursorq[4 * t + 1] = ex + s0;
            cursorq[4 * t + 2] = ex + s0 + s1;
            cursorq[4 * t + 3] = ex + s0 + s1 + s2;
        }
    }
    grid.sync();

    // ---- P3: scatter both clouds ----
    for (int j = gtid; j < M; j += gstride) {
        const float x = pc2[3 * j], y = pc2[3 * j + 1], z = pc2[3 * j + 2];
        const int pos = atomicAdd(&cursor2[slab_of(x)], 1);
        pts2[3 * pos] = x; pts2[3 * pos + 1] = y; pts2[3 * pos + 2] = z;
    }
    for (int j = gtid; j < N; j += gstride) {
        const float x = pc1[3 * j] + flow[3 * j];
        const float y = pc1[3 * j + 1] + flow[3 * j + 1];
        const float z = pc1[3 * j + 2] + flow[3 * j + 2];
        const int pos = atomicAdd(&cursorq[slab_of(x)], 1);
        qs[pos] = make_float4(x, y, z, __int_as_float(j));
    }
    grid.sync();

    // ---- P4: per-group bound + window (group = 64 sorted queries) ----
    const int NG = (N + 63) >> 6;
    const int w = t >> 6, l = t & 63;
    for (int g = b; g < NG; g += GRID) {
        int qi = g * 64 + l; if (qi >= N) qi = N - 1;
        const float4 qf = qs[qi];
        const float qx = qf.x, qy = qf.y, qz = qf.z;

        // bound: 512 rank-near pts, wave w scans its 128
        const float qxm = __shfl(qx, 32, 64);
        int ys = base2[slab_of(qxm)] - 224;
        ys = (ys < 0) ? 0 : ((ys > M - 512) ? M - 512 : ys);
        ys = rfl(ys);
        float m = 3.0e38f;
        {
            const float* yp = upf(pts2 + 3 * (ys + w * 128));
            sf16 A16, B16; sf8 A8, B8;
            SLOAD24(A16, A8, yp, "0", "64");
#pragma unroll 1
            for (int it = 0; it < 8; ++it) {
                SWAIT(A16, A8);
                SLOAD24(B16, B8, yp, "96", "160");
                COMPUTE8_1(A16, A8);
                SWAIT(B16, B8);
                if (it + 1 < 8) SLOAD24(A16, A8, yp, "192", "256");
                COMPUTE8_1(B16, B8);
                yp += 48;
            }
        }
        smem[w][l] = m;
        __syncthreads();
        if (t < 64) {
            const float m4 = fminf(fminf(smem[0][t], smem[1][t]),
                                   fminf(smem[2][t], smem[3][t]));
            sm4[t] = m4;
            float mm = m4;
#pragma unroll
            for (int off = 1; off < 64; off <<= 1)
                mm = fmaxf(mm, __shfl_xor(mm, off, 64));
            if (t == 0) smm = mm;
        }
        __syncthreads();

        // window: proper group min/max of qx (within-slab order is arbitrary!)
        float qmn = qx, qmx = qx;
#pragma unroll
        for (int off = 1; off < 64; off <<= 1) {
            qmn = fminf(qmn, __shfl_xor(qmn, off, 64));
            qmx = fmaxf(qmx, __shfl_xor(qmx, off, 64));
        }
        const float mm = smm;
        int bl = (int)((qmn - mm - LOX) * INVW) - 1;
        bl = (bl < 0) ? 0 : ((bl > NB - 1) ? NB - 1 : bl);
        int br = (int)((qmx + mm - LOX) * INVW) + 1;
        br = (br < 0) ? 0 : ((br > NB - 1) ? NB - 1 : br);
        const int B = base2[bl], E = base2[br + 1];
        const int len = E - B;
        const int j0 = rfl(B + ((len * w) >> 2));
        const int j1 = rfl(B + ((len * (w + 1)) >> 2));
        const int n = j1 - j0;

        m = sm4[l];
        if (n > 0) {
            const int NIT = ((((n + 7) >> 3) + 1) & ~1) >> 1;
            const float* yp = upf(pts2 + 3 * j0);
            sf16 A16, B16; sf8 A8, B8;
            SLOAD24(A16, A8, yp, "0", "64");
#pragma unroll 1
            for (int it = 0; it < NIT; ++it) {
                SWAIT(A16, A8);
                SLOAD24(B16, B8, yp, "96", "160");
                COMPUTE8_1(A16, A8);
                SWAIT(B16, B8);
                if (it + 1 < NIT) SLOAD24(A16, A8, yp, "192", "256");
                COMPUTE8_1(B16, B8);
                yp += 48;
            }
        }
        __syncthreads();           // guard smem reuse across waves
        smem[w][l] = m;
        __syncthreads();
        if (t < 64) {
            const float m4 = fminf(fminf(smem[0][t], smem[1][t]),
                                   fminf(smem[2][t], smem[3][t]));
            qmin[__float_as_int(qf.w)] = m4;
        }
        __syncthreads();
    }
    grid.sync();

    // ---- P5: block 0 sums qmin -> out[0] ----
    if (b == 0) {
        float s = 0.0f;
        const float4* p4 = (const float4*)qmin;
        for (int k = t; k < N / 4; k += TPB) {
            const float4 v = p4[k];
            s += v.x + v.y + v.z + v.w;
        }
        for (int k = (N / 4) * 4 + t; k < N; k += TPB) s += qmin[k];
#pragma unroll
        for (int off = 32; off; off >>= 1) s += __shfl_down(s, off, 64);
        __shared__ float ls[4];
        if ((t & 63) == 0) ls[t >> 6] = s;
        __syncthreads();
        if (t == 0) out[0] = (ls[0] + ls[1] + ls[2] + ls[3]) * invN;
    }
}

extern "C" void kernel_launch(void* const* d_in, const int* in_sizes, int n_in,
                              void* d_out, int out_size, void* d_ws, size_t ws_size,
                              hipStream_t stream) {
    const float* pc1  = (const float*)d_in[0];
    const float* flow = (const float*)d_in[1];
    const float* pc2  = (const float*)d_in[2];
    float* out = (float*)d_out;

    int N = in_sizes[0] / 3;
    int M = in_sizes[2] / 3;

    char* ws = (char*)d_ws;
    int*    hist2   = (int*)(ws + 0);           // 4096 (histq contiguous after)
    int*    histq   = (int*)(ws + 4096);        // 4096
    int*    base2   = (int*)(ws + 8192);        // (NB+1)*4
    int*    cursor2 = (int*)(ws + 16384);       // 4096
    int*    cursorq = (int*)(ws + 20480);       // 4096
    float*  pts2    = (float*)(ws + 24576);     // 3*M*4 + pad
    float4* qs      = (float4*)(ws + 262144);   // N*16
    float*  qmin    = (float*)(ws + 786432);    // N*4

    float invN = 1.0f / (float)N;
    void* args[] = {&pc1, &flow, &pc2, &hist2, &histq, &base2, &cursor2,
                    &cursorq, &pts2, &qs, &qmin, &out, &N, &M,
                    (void*)&out_size, &invN};
    hipLaunchCooperativeKernel((const void*)fused_kernel, dim3(GRID), dim3(TPB),
                               args, 0, stream);
}